// Round 6
// baseline (1202.199 us; speedup 1.0000x reference)
//
#include <hip/hip_runtime.h>

typedef __bf16 bf16;
typedef __bf16 bf16x4 __attribute__((ext_vector_type(4)));
typedef __bf16 bf16x8 __attribute__((ext_vector_type(8)));
typedef float floatx4 __attribute__((ext_vector_type(4)));

#define BB 8
#define LL 2048
#define DD 2048
#define NHH 32
#define HDD 64

#define MFMA16(a, b, c) __builtin_amdgcn_mfma_f32_16x16x32_bf16(a, b, c, 0, 0, 0)

// async global->LDS DMA, 16B per lane; dest = wave-uniform base + lane*16
__device__ __forceinline__ void gl_lds16(const void* g, void* l) {
  __builtin_amdgcn_global_load_lds((const __attribute__((address_space(1))) void*)g,
                                   (__attribute__((address_space(3))) void*)l, 16, 0, 0);
}

// ---------------- fp32 -> bf16 bulk cast (X pre-cast so GEMM A staging can use DMA) ---
__global__ __launch_bounds__(256) void cast_bf16(const float* __restrict__ src,
                                                 bf16* __restrict__ dst)
{
  size_t i = ((size_t)blockIdx.x * 256 + threadIdx.x) * 8;
  floatx4 a = *(const floatx4*)(src + i);
  floatx4 b = *(const floatx4*)(src + i + 4);
  bf16x8 v;
  v[0] = (bf16)a[0]; v[1] = (bf16)a[1]; v[2] = (bf16)a[2]; v[3] = (bf16)a[3];
  v[4] = (bf16)b[0]; v[5] = (bf16)b[1]; v[6] = (bf16)b[2]; v[7] = (bf16)b[3];
  *(bf16x8*)(dst + i) = v;
}

// ---------------- weight transpose + cast: WT[n][k] = (bf16)W[k][n] ----------------
__global__ __launch_bounds__(256) void transpose1(const float* __restrict__ src,
                                                  bf16* __restrict__ dst)
{
  __shared__ float tile[64][65];
  const int t = threadIdx.x;
  const int col = t & 63, rw = t >> 6;
  const int bx = blockIdx.x * 64, by = blockIdx.y * 64;
  for (int i = rw; i < 64; i += 4)
    tile[i][col] = src[(size_t)(by + i) * DD + bx + col];
  __syncthreads();
  for (int i = rw; i < 64; i += 4)
    dst[(size_t)(bx + i) * DD + by + col] = (bf16)tile[col][i];
}

// ---------------- GEMM (known-good): C[16384][2048] = A x B, BT[n][k] bf16 ----
// Staging: global_load_lds dwordx4, linear LDS [128][64], XOR chunk-swizzle
// (chunk ^= row&7) applied to the per-lane GLOBAL source and to the ds_read side.
// RP==1: fuse RoPE into the epilogue (pairs are adjacent lanes; rotate fp32 acc
// before the bf16 store).
template<int AIDX, int EPI, int RP>
__global__ __launch_bounds__(256) void gemm_bt(const bf16* __restrict__ Ab,
    const bf16* __restrict__ BT, void* __restrict__ Cv)
{
  constexpr int Kd = 2048;
  __shared__ alignas(16) bf16 As[128 * 64];
  __shared__ alignas(16) bf16 Bs[128 * 64];
  const int t = threadIdx.x;
  // XCD-aware swizzle: 2048 wgs, 2048%8==0 -> simple remap is bijective.
  const int id = blockIdx.y * 16 + blockIdx.x;
  const int swz = (id & 7) * 256 + (id >> 3);
  const int bn = swz & 15, bm = swz >> 4;
  const int wave = t >> 6, lane = t & 63;
  const int m16 = lane & 15, quad = lane >> 4;
  floatx4 acc[2][8] = {};
  const int r0 = t >> 3;                 // 0..31: row within 32-row stripe
  const int scc = (t & 7) ^ (r0 & 7);    // inverse-swizzled source 16B-chunk
  const bf16* Bb = BT + (size_t)(bn * 128) * Kd;
  char* AsB = (char*)As + wave * 1024;   // wave-uniform DMA dest bases
  char* BsB = (char*)Bs + wave * 1024;

  for (int k0 = 0; k0 < Kd; k0 += 64) {
    for (int i = 0; i < 4; ++i) {
      int r = r0 + 32 * i;
      int col = k0 + scc * 8;
      const bf16* ga;
      if (AIDX == 0) {
        ga = Ab + (size_t)(bm * 128 + r) * Kd + col;
      } else {
        int R = bm * 128 + r;
        int b = R >> 11, l = R & 2047;
        int h = col >> 6, f = col & 63;
        ga = Ab + (((size_t)(b * NHH + h) * LL + l) * HDD + f);
      }
      gl_lds16(ga, AsB + i * 4096);
      gl_lds16(Bb + (size_t)r * Kd + col, BsB + i * 4096);
    }
    __syncthreads();
    const int sw = m16 & 7;
    for (int kk = 0; kk < 2; ++kk) {
      bf16x8 af[2], bfr[8];
      const int c = ((kk * 4 + quad) ^ sw) * 8;
      for (int mt = 0; mt < 2; ++mt)
        af[mt] = *(const bf16x8*)&As[(wave * 32 + mt * 16 + m16) * 64 + c];
      for (int nt = 0; nt < 8; ++nt)
        bfr[nt] = *(const bf16x8*)&Bs[(nt * 16 + m16) * 64 + c];
      for (int mt = 0; mt < 2; ++mt)
        for (int nt = 0; nt < 8; ++nt)
          acc[mt][nt] = MFMA16(af[mt], bfr[nt], acc[mt][nt]);
    }
    __syncthreads();
  }

  float invf[8];
  if (RP) {
#pragma unroll
    for (int nt = 0; nt < 8; ++nt) {
      int col = bn * 128 + nt * 16 + m16;
      int i = (col >> 1) & 31;
      invf[nt] = __expf(-(float)i * 0.28782313662425573f);  // ln(10000)/32
    }
  }

  for (int mt = 0; mt < 2; ++mt)
    for (int nt = 0; nt < 8; ++nt)
      for (int rg = 0; rg < 4; ++rg) {
        int row = bm * 128 + wave * 32 + mt * 16 + quad * 4 + rg;
        int col = bn * 128 + nt * 16 + m16;
        float v = acc[mt][nt][rg];
        if (RP) {
          float o = __shfl_xor(v, 1, 64);        // partner feature of the pair
          float sn, cs;
          __sincosf((float)(row & 2047) * invf[nt], &sn, &cs);
          v = (m16 & 1) ? (v * cs + o * sn) : (v * cs - o * sn);
        }
        if (EPI == 0) {
          ((float*)Cv)[(size_t)row * DD + col] = v;
        } else {
          int b = row >> 11, l = row & 2047;
          int h = col >> 6, f = col & 63;
          ((bf16*)Cv)[((size_t)(b * NHH + h) * LL + l) * HDD + f] = (bf16)v;
        }
      }
}

// ---------------- TTT scan v3: 4 waves, direct-global fragments, 3 barriers/chunk ----
// MFMA operands ak/aq are loaded straight from global memory in fragment layout
// (lane (q,i16) reads row i16, cols q*8 / 32+q*8), prefetched one chunk ahead ->
// no xq/xk LDS staging, no barrier A, no post-barrier ds_read->MFMA chain.
// Z1s double-buffered (removes the E-read vs next-stage1-write hazard barrier A
// protected). All remaining LDS producer/consumer pairs keep >=1 barrier:
//   xkTs: write top-of-iter  -> read stage C   (barriers B,C)
//   Pm  : write stage 1      -> read stage C   (barrier B)
//   gT  : write stage B      -> read stage C   (barrier C)
//   W1T : repack in stage C  -> read next stage1 (barrier D); stage-C readers of
//         old W1T use register copies (whi/wlo) loaded in stage 1.
__global__ __launch_bounds__(256) void ttt_scan(
    const bf16* Q, const bf16* __restrict__ Kx,
    const bf16* __restrict__ V, const float* __restrict__ W1g,
    const float* __restrict__ b1g, const float* __restrict__ gw,
    const float* __restrict__ gb, bf16* O)
{
  const int bh = blockIdx.x, h = bh & 31;
  const int t = threadIdx.x;
  const int wave = t >> 6, lane = t & 63;
  const int q = lane >> 4, i16 = lane & 15;
  const int kr = t >> 4, sr = t & 15, f0 = sr * 4;   // LN mapping: row kr, cols f0..f0+3

  __shared__ alignas(16) bf16 W1Th[64 * 72];   // [g][f] pitch 72 (144B)
  __shared__ alignas(16) bf16 W1Tl[64 * 72];
  __shared__ alignas(16) bf16 xkTs[64 * 24];   // [f][k] = -(1/16)*xk[k][f], pitch 24
  __shared__ alignas(16) bf16 gTh[64 * 24];    // grad^T hi, [g][k]
  __shared__ alignas(16) bf16 gTl[64 * 24];    // grad^T lo
  __shared__ alignas(16) bf16 Pm[16 * 24];     // P[k][l] = -(attn+1)*eta_k (tril)
  __shared__ alignas(16) float Z1s[2][16 * 68]; // fp32 Z1/Zbar roundtrip, double-buffered

  // ---- init state ----
  floatx4 accW[4];                             // W1[16mt+4q+r][16w+i16]
  const float* Wg = W1g + (size_t)h * 4096;
  for (int mt = 0; mt < 4; ++mt)
    for (int r = 0; r < 4; ++r)
      accW[mt][r] = Wg[(16 * mt + 4 * q + r) * 64 + 16 * wave + i16];
  float b1r = b1g[h * 64 + 16 * wave + i16];   // per-lane b1 for col g=16w+i16

  for (int mt = 0; mt < 4; ++mt) {             // initial W1T hi/lo
    bf16x4 h4, l4;
    for (int r = 0; r < 4; ++r) {
      float w = accW[mt][r];
      bf16 hi = (bf16)w;
      h4[r] = hi; l4[r] = (bf16)(w - (float)hi);
    }
    int base = (16 * wave + i16) * 72 + 16 * mt + 4 * q;
    *(bf16x4*)&W1Th[base] = h4;
    *(bf16x4*)&W1Tl[base] = l4;
  }

  float gq[4], bq[4];                          // LN gamma/beta for cols f0..f0+3
  for (int j = 0; j < 4; ++j) {
    gq[j] = gw[h * 64 + f0 + j];
    bq[j] = gb[h * 64 + f0 + j];
  }
  float etar[4];                               // 1/(krow+1), krow = 4q+r (used by wave0)
  for (int r = 0; r < 4; ++r) etar[r] = 1.0f / (float)(4 * q + r + 1);

  const size_t qbase = (size_t)bh * (LL * HDD);
  const int foff = i16 * 64 + q * 8;           // fragment offset within chunk (16B aligned)
  const int poff = kr * 64 + f0;               // per-lane LN offset within chunk

  // prologue: chunk 0 into regs (fragments + per-lane LN slices)
  bf16x8 ak0 = *(const bf16x8*)(Kx + qbase + foff);
  bf16x8 ak1 = *(const bf16x8*)(Kx + qbase + foff + 32);
  bf16x8 aq0 = *(const bf16x8*)(Q  + qbase + foff);
  bf16x8 aq1 = *(const bf16x8*)(Q  + qbase + foff + 32);
  bf16x4 rq = *(const bf16x4*)(Q  + qbase + poff);
  bf16x4 rk = *(const bf16x4*)(Kx + qbase + poff);
  bf16x4 rv = *(const bf16x4*)(V  + qbase + poff);

  __syncthreads();   // W1T init visible

  for (int c = 0; c < 128; ++c) {
    const int pb = c & 1;
    // ---- xkT scatter (readers in stage C; barriers B,C intervene) ----
    for (int j = 0; j < 4; ++j)
      xkTs[(f0 + j) * 24 + kr] = (bf16)((float)rk[j] * -0.0625f);  // exact pow2 scale

    // ---- stage 1: Z1 = xk @ W1 + b1 (all waves); attn -> P (wave 0) ----
    bf16x8 whi[2], wlo[2];
    {
      int wb = (16 * wave + i16) * 72 + q * 8;
      whi[0] = *(const bf16x8*)&W1Th[wb];
      whi[1] = *(const bf16x8*)&W1Th[wb + 32];
      wlo[0] = *(const bf16x8*)&W1Tl[wb];
      wlo[1] = *(const bf16x8*)&W1Tl[wb + 32];
    }
    {
      floatx4 z = {b1r, b1r, b1r, b1r};
      z = MFMA16(ak0, whi[0], z);
      z = MFMA16(ak1, whi[1], z);
      z = MFMA16(ak0, wlo[0], z);
      z = MFMA16(ak1, wlo[1], z);
      for (int r = 0; r < 4; ++r)
        Z1s[pb][(4 * q + r) * 68 + 16 * wave + i16] = z[r];
    }
    if (wave == 0) {
      floatx4 at = {};
      at = MFMA16(aq0, ak0, at);
      at = MFMA16(aq1, ak1, at);
      for (int r = 0; r < 4; ++r) {
        int krow = 4 * q + r;
        float pv = (i16 <= krow) ? -(at[r] + 1.0f) * etar[r] : 0.0f;
        Pm[krow * 24 + i16] = (bf16)pv;
      }
    }
    __syncthreads();   // barrier B

    // ---- stage B: LN fused-l2 backward -> grad^T hi/lo ----
    {
      floatx4 z4 = *(const floatx4*)&Z1s[pb][kr * 68 + f0];
      float tg[4], sum = 0.f, ssq = 0.f;
      for (int j = 0; j < 4; ++j) {
        tg[j] = (float)rv[j] - (float)rk[j];
        sum += z4[j]; ssq += z4[j] * z4[j];
      }
      for (int m = 1; m < 16; m <<= 1) { sum += __shfl_xor(sum, m, 64); ssq += __shfl_xor(ssq, m, 64); }
      float mu = sum * (1.f / 64.f);
      float var = ssq * (1.f / 64.f) - mu * mu;
      float rstd = rsqrtf(var + 1e-6f);
      float xh[4], gx[4], s1 = 0.f, s2 = 0.f;
      for (int j = 0; j < 4; ++j) {
        xh[j] = (z4[j] - mu) * rstd;
        float go = gq[j] * xh[j] + bq[j] - tg[j];
        gx[j] = go * gq[j];
        s1 += gx[j]; s2 += gx[j] * xh[j];
      }
      for (int m = 1; m < 16; m <<= 1) { s1 += __shfl_xor(s1, m, 64); s2 += __shfl_xor(s2, m, 64); }
      for (int j = 0; j < 4; ++j) {
        float gr = (64.f * gx[j] - s1 - xh[j] * s2) * (rstd * (1.f / 64.f));
        bf16 hi = (bf16)gr;
        gTh[(f0 + j) * 24 + kr] = hi;
        gTl[(f0 + j) * 24 + kr] = (bf16)(gr - (float)hi);
      }
    }
    __syncthreads();   // barrier C

    // ---- prefetch chunk c+1 (c=127 reads spill harmlessly into adjacent buffers) ----
    const size_t nb = qbase + (size_t)(c + 1) * 1024;
    bf16x8 nak0 = *(const bf16x8*)(Kx + nb + foff);
    bf16x8 nak1 = *(const bf16x8*)(Kx + nb + foff + 32);
    bf16x8 naq0 = *(const bf16x8*)(Q  + nb + foff);
    bf16x8 naq1 = *(const bf16x8*)(Q  + nb + foff + 32);
    bf16x4 nrq = *(const bf16x4*)(Q  + nb + poff);
    bf16x4 nrk = *(const bf16x4*)(Kx + nb + poff);
    bf16x4 nrv = *(const bf16x4*)(V  + nb + poff);

    // ---- stage C: Zbar = xq@W1 + P@grad + b1 ; accW update; W1T repack; b1 ----
    {
      bf16x8 pf  = *(const bf16x8*)&Pm[i16 * 24 + (q & 1) * 8];
      const bf16* gT = (q < 2) ? gTh : gTl;    // K=32 packing: hi halves then lo halves
      bf16x8 bgp = *(const bf16x8*)&gT[(16 * wave + i16) * 24 + (q & 1) * 8];
      floatx4 zb = {b1r, b1r, b1r, b1r};
      zb = MFMA16(aq0, whi[0], zb);
      zb = MFMA16(aq1, whi[1], zb);
      zb = MFMA16(aq0, wlo[0], zb);
      zb = MFMA16(aq1, wlo[1], zb);
      zb = MFMA16(pf, bgp, zb);                // sums P*(grad_hi+grad_lo)
      for (int r = 0; r < 4; ++r)
        Z1s[pb][(4 * q + r) * 68 + 16 * wave + i16] = zb[r];

      for (int mt = 0; mt < 4; ++mt) {
        bf16x8 axk = *(const bf16x8*)&xkTs[(16 * mt + i16) * 24 + (q & 1) * 8];
        accW[mt] = MFMA16(axk, bgp, accW[mt]);
      }
      for (int mt = 0; mt < 4; ++mt) {         // repack new W1T (readers after barrier D)
        bf16x4 h4, l4;
        for (int r = 0; r < 4; ++r) {
          float w = accW[mt][r];
          bf16 hi = (bf16)w;
          h4[r] = hi; l4[r] = (bf16)(w - (float)hi);
        }
        int base = (16 * wave + i16) * 72 + 16 * mt + 4 * q;
        *(bf16x4*)&W1Th[base] = h4;
        *(bf16x4*)&W1Tl[base] = l4;
      }
      {
        const bf16* rh = &gTh[(16 * wave + i16) * 24];
        const bf16* rl = &gTl[(16 * wave + i16) * 24];
        bf16x8 a0 = *(const bf16x8*)rh, a1 = *(const bf16x8*)(rh + 8);
        bf16x8 a2 = *(const bf16x8*)rl, a3 = *(const bf16x8*)(rl + 8);
        float s = 0.f;
        for (int j = 0; j < 8; ++j)
          s += (float)a0[j] + (float)a1[j] + (float)a2[j] + (float)a3[j];
        b1r -= 0.0625f * s;
      }
    }
    __syncthreads();   // barrier D

    // ---- stage E: out = xq + LN_fwd(Zbar) -> O (aliases Q) ----
    {
      floatx4 z4 = *(const floatx4*)&Z1s[pb][kr * 68 + f0];
      float sum = 0.f, ssq = 0.f;
      for (int j = 0; j < 4; ++j) { sum += z4[j]; ssq += z4[j] * z4[j]; }
      for (int m = 1; m < 16; m <<= 1) { sum += __shfl_xor(sum, m, 64); ssq += __shfl_xor(ssq, m, 64); }
      float mu = sum * (1.f / 64.f);
      float var = ssq * (1.f / 64.f) - mu * mu;
      float rstd = rsqrtf(var + 1e-6f);
      bf16x4 o4;
      for (int j = 0; j < 4; ++j)
        o4[j] = (bf16)((float)rq[j] + gq[j] * ((z4[j] - mu) * rstd) + bq[j]);
      *(bf16x4*)(O + qbase + (size_t)c * 1024 + poff) = o4;
    }
    ak0 = nak0; ak1 = nak1; aq0 = naq0; aq1 = naq1;
    rq = nrq; rk = nrk; rv = nrv;
    // no barrier: next iteration writes Z1s[pb^1]; xkTs/Pm/gT/W1T pairs all retain
    // >=1 barrier as documented above.
  }
}

extern "C" void kernel_launch(void* const* d_in, const int* in_sizes, int n_in,
                              void* d_out, int out_size, void* d_ws, size_t ws_size,
                              hipStream_t stream)
{
  const float* X  = (const float*)d_in[0];
  const float* wq = (const float*)d_in[1];
  const float* wk = (const float*)d_in[2];
  const float* wv = (const float*)d_in[3];
  const float* wo = (const float*)d_in[4];
  const float* W1 = (const float*)d_in[5];
  const float* b1 = (const float*)d_in[6];
  const float* gw = (const float*)d_in[7];
  const float* gb = (const float*)d_in[8];

  bf16* ws = (bf16*)d_ws;
  const size_t NEl = (size_t)BB * LL * DD;   // 33,554,432 elems per tensor
  bf16* Qb = ws;                 // also the scan output O (aliased)
  bf16* Kb = ws + NEl;
  bf16* WT = ws + 2 * NEl;       // single 2048x2048 transposed bf16 weight slot, reused
  bf16* Vb = (bf16*)d_out;       // V bf16 (64 MB) in d_out's first half (d_out = 128 MB fp32)
  bf16* Xb = (bf16*)d_out + NEl; // X bf16 (64 MB) in d_out's second half; both are fully
                                 // consumed before the final GEMM overwrites d_out.

  cast_bf16<<<dim3(16384), 256, 0, stream>>>(X, Xb);
  transpose1<<<dim3(32, 32), 256, 0, stream>>>(wq, WT);
  gemm_bt<0, 1, 1><<<dim3(16, 128), 256, 0, stream>>>(Xb, WT, Qb);   // Q + fused RoPE
  transpose1<<<dim3(32, 32), 256, 0, stream>>>(wk, WT);
  gemm_bt<0, 1, 1><<<dim3(16, 128), 256, 0, stream>>>(Xb, WT, Kb);   // K + fused RoPE
  transpose1<<<dim3(32, 32), 256, 0, stream>>>(wv, WT);
  gemm_bt<0, 1, 0><<<dim3(16, 128), 256, 0, stream>>>(Xb, WT, Vb);   // V
  ttt_scan<<<dim3(256), 256, 0, stream>>>(Qb, Kb, Vb, W1, b1, gw, gb, Qb);
  transpose1<<<dim3(32, 32), 256, 0, stream>>>(wo, WT);
  gemm_bt<1, 0, 0><<<dim3(16, 128), 256, 0, stream>>>(Qb, WT, d_out);
}